// Round 1
// baseline (1092.436 us; speedup 1.0000x reference)
//
#include <hip/hip_runtime.h>
#include <hip/hip_bf16.h>
#include <stdint.h>

#define T_TOK 8192
#define DDIM 2048
#define IDIM 2048
#define NEXP 8
#define NPAIR (T_TOK*2)             // 16384
#define MAXROWS (NPAIR + NEXP*128)  // 17408
#define MAXTILES (MAXROWS/128)      // 136

typedef __attribute__((ext_vector_type(8))) short short8;   // 8 bf16 (4 VGPRs)
typedef __attribute__((ext_vector_type(4))) float f32x4;

__device__ __forceinline__ ushort f2bf(float f) {
  union { float f; unsigned int u; } v; v.f = f;
  unsigned int u = v.u;
  unsigned int r = (u + 0x7fffu + ((u >> 16) & 1u)) >> 16;  // RNE
  return (ushort)r;
}

__device__ __forceinline__ void glds16(const void* g, void* l) {
  __builtin_amdgcn_global_load_lds(
      (const __attribute__((address_space(1))) unsigned int*)g,
      (__attribute__((address_space(3))) unsigned int*)l, 16, 0, 0);
}

// ---------------- router: top-2 + softmax weights ----------------
__global__ void router_kernel(const float* __restrict__ logits, int* __restrict__ pair_e,
                              float* __restrict__ pair_w, int* __restrict__ cnt) {
  __shared__ int c[NEXP];
  int tid = threadIdx.x;
  int t = blockIdx.x * 256 + tid;
  if (tid < NEXP) c[tid] = 0;
  __syncthreads();
  float lv[NEXP];
  #pragma unroll
  for (int e = 0; e < NEXP; ++e) lv[e] = logits[t * NEXP + e];
  int i0 = 0;
  #pragma unroll
  for (int e = 1; e < NEXP; ++e) if (lv[e] > lv[i0]) i0 = e;
  int i1 = (i0 == 0) ? 1 : 0;
  #pragma unroll
  for (int e = 0; e < NEXP; ++e) if (e != i0 && lv[e] > lv[i1]) i1 = e;
  float ex = __expf(lv[i1] - lv[i0]);         // <= 1
  float w1 = ex / (1.f + ex);
  float w0 = 1.f - w1;
  pair_e[2*t] = i0; pair_e[2*t+1] = i1;
  pair_w[2*t] = w0; pair_w[2*t+1] = w1;
  atomicAdd(&c[i0], 1); atomicAdd(&c[i1], 1);
  __syncthreads();
  if (tid < NEXP) atomicAdd(&cnt[tid], c[tid]);
}

// ---------------- scan: padded offsets (multiples of 128) ----------------
__global__ void scan_kernel(const int* __restrict__ cnt, int* __restrict__ poff) {
  if (threadIdx.x == 0 && blockIdx.x == 0) {
    int o = 0; poff[0] = 0;
    for (int e = 0; e < NEXP; ++e) { o += (cnt[e] + 127) & ~127; poff[e+1] = o; }
  }
}

// ---------------- scatter pairs into grouped slots ----------------
__global__ void scatter_kernel(const int* __restrict__ pair_e, const float* __restrict__ pair_w,
                               const int* __restrict__ poff, int* __restrict__ fill,
                               int* __restrict__ row_token, float* __restrict__ row_weight) {
  __shared__ int lc[NEXP], lb[NEXP];
  int tid = threadIdx.x;
  int t = blockIdx.x * 256 + tid;
  if (tid < NEXP) lc[tid] = 0;
  __syncthreads();
  int e0 = pair_e[2*t], e1 = pair_e[2*t+1];
  int r0 = atomicAdd(&lc[e0], 1);
  int r1 = atomicAdd(&lc[e1], 1);
  __syncthreads();
  if (tid < NEXP) lb[tid] = atomicAdd(&fill[tid], lc[tid]);
  __syncthreads();
  int p0 = poff[e0] + lb[e0] + r0;
  int p1 = poff[e1] + lb[e1] + r1;
  row_token[p0] = t; row_weight[p0] = pair_w[2*t];
  row_token[p1] = t; row_weight[p1] = pair_w[2*t+1];
}

// ---------------- x fp32 -> bf16 ----------------
__global__ void convert_x_kernel(const float* __restrict__ x, ushort* __restrict__ xb) {
  size_t i = ((size_t)blockIdx.x * 256 + threadIdx.x) * 8;
  float4 a = *(const float4*)(x + i);
  float4 b = *(const float4*)(x + i + 4);
  uint4 o;
  o.x = (unsigned)f2bf(a.x) | ((unsigned)f2bf(a.y) << 16);
  o.y = (unsigned)f2bf(a.z) | ((unsigned)f2bf(a.w) << 16);
  o.z = (unsigned)f2bf(b.x) | ((unsigned)f2bf(b.y) << 16);
  o.w = (unsigned)f2bf(b.z) | ((unsigned)f2bf(b.w) << 16);
  *(uint4*)(xb + i) = o;
}

// ---------------- weights fp32 [k][n] -> bf16 transposed [n][k] ----------------
__global__ void transpose_w_kernel(const float* __restrict__ wi0, const float* __restrict__ wi1,
                                   const float* __restrict__ wo, ushort* __restrict__ w0t,
                                   ushort* __restrict__ w1t, ushort* __restrict__ wot) {
  int mz = blockIdx.z;
  int mat = mz >> 3, e = mz & 7;
  const float* src = (mat == 0 ? wi0 : (mat == 1 ? wi1 : wo)) + (size_t)e * DDIM * IDIM;
  ushort* dst = (mat == 0 ? w0t : (mat == 1 ? w1t : wot)) + (size_t)e * DDIM * IDIM;
  __shared__ ushort tbuf[64][72];   // padded stride: 144B, 16B-aligned rows
  int tid = threadIdx.x;
  int bi = blockIdx.x, bj = blockIdx.y;       // bi: k-tile, bj: n-tile
  int rl = tid >> 4;
  int cl = (tid & 15) * 4;
  #pragma unroll
  for (int it = 0; it < 4; ++it) {
    int r = rl + it * 16;
    float4 v = *(const float4*)(src + (size_t)(bi*64 + r) * 2048 + bj*64 + cl);
    tbuf[cl+0][r] = f2bf(v.x);
    tbuf[cl+1][r] = f2bf(v.y);
    tbuf[cl+2][r] = f2bf(v.z);
    tbuf[cl+3][r] = f2bf(v.w);
  }
  __syncthreads();
  int n = tid >> 2, ch = tid & 3;
  const ushort* p = &tbuf[n][ch*16];
  unsigned pk[8];
  #pragma unroll
  for (int j = 0; j < 8; ++j) pk[j] = (unsigned)p[2*j] | ((unsigned)p[2*j+1] << 16);
  ushort* d = dst + (size_t)(bj*64 + n) * 2048 + bi*64 + ch*16;
  uint4 o0, o1;
  o0.x = pk[0]; o0.y = pk[1]; o0.z = pk[2]; o0.w = pk[3];
  o1.x = pk[4]; o1.y = pk[5]; o1.z = pk[6]; o1.w = pk[7];
  *(uint4*)(d) = o0;
  *(uint4*)(d + 8) = o1;
}

// ---------------- GEMM1: inter = silu(x@wi0) * (x@wi1), grouped ----------------
__global__ __launch_bounds__(256, 2) void gemm1_kernel(
    const ushort* __restrict__ xb, const ushort* __restrict__ w0t,
    const ushort* __restrict__ w1t, const int* __restrict__ row_token,
    const int* __restrict__ poff, ushort* __restrict__ inter) {
  const int rt = blockIdx.x, ct = blockIdx.y;
  const int row0 = rt * 128;
  if (row0 >= poff[NEXP]) return;
  int e = 0;
  #pragma unroll
  for (int i = 1; i < NEXP; ++i) e += (row0 >= poff[i]);

  __shared__ __align__(16) char smem[2 * 24576];   // 2 bufs x (A 8K | B0 8K | B1 8K)
  const int tid = threadIdx.x;
  const int w = tid >> 6, l = tid & 63;

  // staging precompute: linear LDS chunk -> swizzled global source
  const ushort* aSrc[2]; const ushort* b0Src[2]; const ushort* b1Src[2];
  int ldsOff[2];
  #pragma unroll
  for (int c = 0; c < 2; ++c) {
    int o = c * 4096 + w * 1024 + l * 16;     // byte offset in 8KB tile
    int m = o >> 6;                           // tile row 0..127
    int ci = (o >> 4) & 3;                    // 16B chunk in row
    int kl = ((ci ^ ((m >> 1) & 3)) << 3);    // element offset (swizzle involution)
    ldsOff[c] = c * 4096 + w * 1024;          // wave-uniform dest base
    int tok = row_token[row0 + m];
    aSrc[c]  = xb  + (size_t)tok * DDIM + kl;
    int n = ct * 128 + m;
    b0Src[c] = w0t + ((size_t)e * IDIM + n) * DDIM + kl;
    b1Src[c] = w1t + ((size_t)e * IDIM + n) * DDIM + kl;
  }

  f32x4 acc0[4][4], acc1[4][4];
  #pragma unroll
  for (int i = 0; i < 4; ++i)
    #pragma unroll
    for (int j = 0; j < 4; ++j) { acc0[i][j] = (f32x4)(0.f); acc1[i][j] = (f32x4)(0.f); }

  const int wr = w >> 1, wc = w & 1;
  const int fr = l & 15, kq = l >> 4;
  int aOff[4], bOff[4];
  #pragma unroll
  for (int mi = 0; mi < 4; ++mi) {
    int m = wr * 64 + mi * 16 + fr;
    aOff[mi] = m * 64 + ((kq * 16) ^ (((m >> 1) & 3) << 4));
  }
  #pragma unroll
  for (int ni = 0; ni < 4; ++ni) {
    int n = wc * 64 + ni * 16 + fr;
    bOff[ni] = n * 64 + ((kq * 16) ^ (((n >> 1) & 3) << 4));
  }

  const int NT = DDIM / 32;
  #pragma unroll
  for (int c = 0; c < 2; ++c) {
    glds16(aSrc[c],  smem + 0     + ldsOff[c]);
    glds16(b0Src[c], smem + 8192  + ldsOff[c]);
    glds16(b1Src[c], smem + 16384 + ldsOff[c]);
  }
  __syncthreads();

  int buf = 0;
  for (int kt = 0; kt < NT; ++kt) {
    if (kt + 1 < NT) {
      char* base = smem + (buf ^ 1) * 24576;
      int kadv = (kt + 1) * 32;
      #pragma unroll
      for (int c = 0; c < 2; ++c) {
        glds16(aSrc[c]  + kadv, base + 0     + ldsOff[c]);
        glds16(b0Src[c] + kadv, base + 8192  + ldsOff[c]);
        glds16(b1Src[c] + kadv, base + 16384 + ldsOff[c]);
      }
    }
    const char* cb = smem + buf * 24576;
    short8 a[4], b0[4], b1[4];
    #pragma unroll
    for (int mi = 0; mi < 4; ++mi) a[mi] = *(const short8*)(cb + aOff[mi]);
    #pragma unroll
    for (int ni = 0; ni < 4; ++ni) {
      b0[ni] = *(const short8*)(cb + 8192  + bOff[ni]);
      b1[ni] = *(const short8*)(cb + 16384 + bOff[ni]);
    }
    #pragma unroll
    for (int mi = 0; mi < 4; ++mi)
      #pragma unroll
      for (int ni = 0; ni < 4; ++ni) {
        acc0[mi][ni] = __builtin_amdgcn_mfma_f32_16x16x32_bf16(a[mi], b0[ni], acc0[mi][ni], 0, 0, 0);
        acc1[mi][ni] = __builtin_amdgcn_mfma_f32_16x16x32_bf16(a[mi], b1[ni], acc1[mi][ni], 0, 0, 0);
      }
    __syncthreads();
    buf ^= 1;
  }

  #pragma unroll
  for (int mi = 0; mi < 4; ++mi)
    #pragma unroll
    for (int ni = 0; ni < 4; ++ni) {
      int col = ct * 128 + wc * 64 + ni * 16 + fr;
      #pragma unroll
      for (int j = 0; j < 4; ++j) {
        int row = row0 + wr * 64 + mi * 16 + kq * 4 + j;
        float h0 = acc0[mi][ni][j];
        float h1 = acc1[mi][ni][j];
        float s = h0 / (1.f + __expf(-h0));
        inter[(size_t)row * IDIM + col] = f2bf(s * h1);
      }
    }
}

// ---------------- GEMM2: out += w * (inter @ wo), grouped, atomic combine ----------------
__global__ __launch_bounds__(256, 2) void gemm2_kernel(
    const ushort* __restrict__ inter, const ushort* __restrict__ wot,
    const int* __restrict__ row_token, const float* __restrict__ row_weight,
    const int* __restrict__ poff, float* __restrict__ dout) {
  const int rt = blockIdx.x, ct = blockIdx.y;
  const int row0 = rt * 128;
  if (row0 >= poff[NEXP]) return;
  int e = 0;
  #pragma unroll
  for (int i = 1; i < NEXP; ++i) e += (row0 >= poff[i]);

  __shared__ __align__(16) char smem[2 * 16384];   // 2 bufs x (A 8K | B 8K)
  __shared__ int tok_s[128];
  __shared__ float wgt_s[128];
  const int tid = threadIdx.x;
  if (tid < 128) { tok_s[tid] = row_token[row0 + tid]; wgt_s[tid] = row_weight[row0 + tid]; }

  const int w = tid >> 6, l = tid & 63;
  const ushort* aSrc[2]; const ushort* bSrc[2];
  int ldsOff[2];
  #pragma unroll
  for (int c = 0; c < 2; ++c) {
    int o = c * 4096 + w * 1024 + l * 16;
    int m = o >> 6;
    int ci = (o >> 4) & 3;
    int kl = ((ci ^ ((m >> 1) & 3)) << 3);
    ldsOff[c] = c * 4096 + w * 1024;
    aSrc[c] = inter + (size_t)(row0 + m) * IDIM + kl;
    bSrc[c] = wot + ((size_t)e * DDIM + ct * 128 + m) * IDIM + kl;
  }

  f32x4 acc[4][4];
  #pragma unroll
  for (int i = 0; i < 4; ++i)
    #pragma unroll
    for (int j = 0; j < 4; ++j) acc[i][j] = (f32x4)(0.f);

  const int wr = w >> 1, wc = w & 1;
  const int fr = l & 15, kq = l >> 4;
  int aOff[4], bOff[4];
  #pragma unroll
  for (int mi = 0; mi < 4; ++mi) {
    int m = wr * 64 + mi * 16 + fr;
    aOff[mi] = m * 64 + ((kq * 16) ^ (((m >> 1) & 3) << 4));
  }
  #pragma unroll
  for (int ni = 0; ni < 4; ++ni) {
    int n = wc * 64 + ni * 16 + fr;
    bOff[ni] = n * 64 + ((kq * 16) ^ (((n >> 1) & 3) << 4));
  }

  const int NT = IDIM / 32;
  #pragma unroll
  for (int c = 0; c < 2; ++c) {
    glds16(aSrc[c], smem + 0    + ldsOff[c]);
    glds16(bSrc[c], smem + 8192 + ldsOff[c]);
  }
  __syncthreads();

  int buf = 0;
  for (int kt = 0; kt < NT; ++kt) {
    if (kt + 1 < NT) {
      char* base = smem + (buf ^ 1) * 16384;
      int kadv = (kt + 1) * 32;
      #pragma unroll
      for (int c = 0; c < 2; ++c) {
        glds16(aSrc[c] + kadv, base + 0    + ldsOff[c]);
        glds16(bSrc[c] + kadv, base + 8192 + ldsOff[c]);
      }
    }
    const char* cb = smem + buf * 16384;
    short8 a[4], b[4];
    #pragma unroll
    for (int mi = 0; mi < 4; ++mi) a[mi] = *(const short8*)(cb + aOff[mi]);
    #pragma unroll
    for (int ni = 0; ni < 4; ++ni) b[ni] = *(const short8*)(cb + 8192 + bOff[ni]);
    #pragma unroll
    for (int mi = 0; mi < 4; ++mi)
      #pragma unroll
      for (int ni = 0; ni < 4; ++ni)
        acc[mi][ni] = __builtin_amdgcn_mfma_f32_16x16x32_bf16(a[mi], b[ni], acc[mi][ni], 0, 0, 0);
    __syncthreads();
    buf ^= 1;
  }

  #pragma unroll
  for (int mi = 0; mi < 4; ++mi)
    #pragma unroll
    for (int ni = 0; ni < 4; ++ni) {
      int col = ct * 128 + wc * 64 + ni * 16 + fr;
      #pragma unroll
      for (int j = 0; j < 4; ++j) {
        int rl2 = wr * 64 + mi * 16 + kq * 4 + j;
        float wv = wgt_s[rl2];
        if (wv != 0.f) {
          int t = tok_s[rl2];
          atomicAdd(&dout[(size_t)t * DDIM + col], wv * acc[mi][ni][j]);
        }
      }
    }
}

extern "C" void kernel_launch(void* const* d_in, const int* in_sizes, int n_in,
                              void* d_out, int out_size, void* d_ws, size_t ws_size,
                              hipStream_t stream) {
  const float* x   = (const float*)d_in[0];
  const float* rl  = (const float*)d_in[1];
  const float* wi0 = (const float*)d_in[2];
  const float* wi1 = (const float*)d_in[3];
  const float* wo  = (const float*)d_in[4];
  float* out = (float*)d_out;

  char* ws = (char*)d_ws;
  ushort* xb    = (ushort*)(ws);                 // 33,554,432 B
  ushort* w0t   = (ushort*)(ws + 33554432ull);   // 67,108,864 B
  ushort* w1t   = (ushort*)(ws + 100663296ull);
  ushort* wot   = (ushort*)(ws + 167772160ull);
  ushort* inter = (ushort*)(ws + 234881024ull);  // 71,303,168 B
  char* ctrl    = ws + 306184192ull;
  int*   row_token  = (int*)(ctrl);              // 69,632 B
  float* row_weight = (float*)(ctrl + 69632);    // 69,632 B
  int*   cnt   = (int*)(ctrl + 139264);          // 32 B
  int*   fill  = (int*)(ctrl + 139296);          // 32 B
  int*   poff  = (int*)(ctrl + 139328);          // 36 B
  int*   pair_e = (int*)(ctrl + 139392);         // 65,536 B
  float* pair_w = (float*)(ctrl + 204928);       // 65,536 B

  hipMemsetAsync(ctrl, 0, 139328, stream);       // row_token/row_weight/cnt/fill
  router_kernel<<<T_TOK/256, 256, 0, stream>>>(rl, pair_e, pair_w, cnt);
  scan_kernel<<<1, 64, 0, stream>>>(cnt, poff);
  scatter_kernel<<<T_TOK/256, 256, 0, stream>>>(pair_e, pair_w, poff, fill, row_token, row_weight);
  convert_x_kernel<<<(T_TOK*DDIM)/(256*8), 256, 0, stream>>>(x, xb);
  transpose_w_kernel<<<dim3(32, 32, 24), 256, 0, stream>>>(wi0, wi1, wo, w0t, w1t, wot);
  hipMemsetAsync(d_out, 0, (size_t)out_size * sizeof(float), stream);
  gemm1_kernel<<<dim3(MAXTILES, 16), 256, 0, stream>>>(xb, w0t, w1t, row_token, poff, inter);
  gemm2_kernel<<<dim3(MAXTILES, 16), 256, 0, stream>>>(inter, wot, row_token, row_weight, poff, out);
}

// Round 3
// 985.911 us; speedup vs baseline: 1.1080x; 1.1080x over previous
//
#include <hip/hip_runtime.h>
#include <hip/hip_bf16.h>
#include <stdint.h>

#define T_TOK 8192
#define DDIM 2048
#define IDIM 2048
#define NEXP 8
#define NPAIR (T_TOK*2)              // 16384
#define MAXROWS (NPAIR + NEXP*256)   // 18432 (rows padded to 256 per expert)
#define RTILES (MAXROWS/256)         // 72
#define NTK 32                       // K tiles: 2048/64

typedef __attribute__((ext_vector_type(8))) short short8;   // 8 bf16
typedef __attribute__((ext_vector_type(4))) float f32x4;

__device__ __forceinline__ ushort f2bf(float f) {
  union { float f; unsigned int u; } v; v.f = f;
  unsigned int u = v.u;
  unsigned int r = (u + 0x7fffu + ((u >> 16) & 1u)) >> 16;  // RNE
  return (ushort)r;
}

__device__ __forceinline__ void glds16(const void* g, void* l) {
  __builtin_amdgcn_global_load_lds(
      (const __attribute__((address_space(1))) unsigned int*)g,
      (__attribute__((address_space(3))) unsigned int*)l, 16, 0, 0);
}

#define BAR() __builtin_amdgcn_s_barrier()
#define VMC6() asm volatile("s_waitcnt vmcnt(6)" ::: "memory")
#define VMC4() asm volatile("s_waitcnt vmcnt(4)" ::: "memory")
#define VMC0() asm volatile("s_waitcnt vmcnt(0)" ::: "memory")

// ---------------- router: top-2 + softmax weights ----------------
__global__ void router_kernel(const float* __restrict__ logits, int* __restrict__ pair_e,
                              float* __restrict__ pair_w, int* __restrict__ cnt) {
  __shared__ int c[NEXP];
  int tid = threadIdx.x;
  int t = blockIdx.x * 256 + tid;
  if (tid < NEXP) c[tid] = 0;
  __syncthreads();
  float lv[NEXP];
  #pragma unroll
  for (int e = 0; e < NEXP; ++e) lv[e] = logits[t * NEXP + e];
  int i0 = 0;
  #pragma unroll
  for (int e = 1; e < NEXP; ++e) if (lv[e] > lv[i0]) i0 = e;
  int i1 = (i0 == 0) ? 1 : 0;
  #pragma unroll
  for (int e = 0; e < NEXP; ++e) if (e != i0 && lv[e] > lv[i1]) i1 = e;
  float ex = __expf(lv[i1] - lv[i0]);
  float w1 = ex / (1.f + ex);
  float w0 = 1.f - w1;
  pair_e[2*t] = i0; pair_e[2*t+1] = i1;
  pair_w[2*t] = w0; pair_w[2*t+1] = w1;
  atomicAdd(&c[i0], 1); atomicAdd(&c[i1], 1);
  __syncthreads();
  if (tid < NEXP) atomicAdd(&cnt[tid], c[tid]);
}

// ---------------- scan: padded offsets (multiples of 256) ----------------
__global__ void scan_kernel(const int* __restrict__ cnt, int* __restrict__ poff) {
  if (threadIdx.x == 0 && blockIdx.x == 0) {
    int o = 0; poff[0] = 0;
    for (int e = 0; e < NEXP; ++e) { o += (cnt[e] + 255) & ~255; poff[e+1] = o; }
  }
}

// ---------------- scatter pairs into grouped slots ----------------
__global__ void scatter_kernel(const int* __restrict__ pair_e, const float* __restrict__ pair_w,
                               const int* __restrict__ poff, int* __restrict__ fill,
                               int* __restrict__ row_token, float* __restrict__ row_weight) {
  __shared__ int lc[NEXP], lb[NEXP];
  int tid = threadIdx.x;
  int t = blockIdx.x * 256 + tid;
  if (tid < NEXP) lc[tid] = 0;
  __syncthreads();
  int e0 = pair_e[2*t], e1 = pair_e[2*t+1];
  int r0 = atomicAdd(&lc[e0], 1);
  int r1 = atomicAdd(&lc[e1], 1);
  __syncthreads();
  if (tid < NEXP) lb[tid] = atomicAdd(&fill[tid], lc[tid]);
  __syncthreads();
  int p0 = poff[e0] + lb[e0] + r0;
  int p1 = poff[e1] + lb[e1] + r1;
  row_token[p0] = t; row_weight[p0] = pair_w[2*t];
  row_token[p1] = t; row_weight[p1] = pair_w[2*t+1];
}

// ---------------- x fp32 -> bf16 ----------------
__global__ void convert_x_kernel(const float* __restrict__ x, ushort* __restrict__ xb) {
  size_t i = ((size_t)blockIdx.x * 256 + threadIdx.x) * 8;
  float4 a = *(const float4*)(x + i);
  float4 b = *(const float4*)(x + i + 4);
  uint4 o;
  o.x = (unsigned)f2bf(a.x) | ((unsigned)f2bf(a.y) << 16);
  o.y = (unsigned)f2bf(a.z) | ((unsigned)f2bf(a.w) << 16);
  o.z = (unsigned)f2bf(b.x) | ((unsigned)f2bf(b.y) << 16);
  o.w = (unsigned)f2bf(b.z) | ((unsigned)f2bf(b.w) << 16);
  *(uint4*)(xb + i) = o;
}

// ---------------- weights fp32 [k][n] -> bf16 transposed [n][k] ----------------
// mat = blockIdx.z>>3 selects (s0,d0) or (s1,d1); e = blockIdx.z&7
__global__ void transpose_w_kernel(const float* __restrict__ s0, ushort* __restrict__ d0,
                                   const float* __restrict__ s1, ushort* __restrict__ d1) {
  int mz = blockIdx.z;
  int mat = mz >> 3, e = mz & 7;
  const float* src = (mat ? s1 : s0) + (size_t)e * DDIM * IDIM;
  ushort* dst = (mat ? d1 : d0) + (size_t)e * DDIM * IDIM;
  __shared__ ushort tbuf[64][72];
  int tid = threadIdx.x;
  int bi = blockIdx.x, bj = blockIdx.y;       // bi: k-tile, bj: n-tile
  int rl = tid >> 4;
  int cl = (tid & 15) * 4;
  #pragma unroll
  for (int it = 0; it < 4; ++it) {
    int r = rl + it * 16;
    float4 v = *(const float4*)(src + (size_t)(bi*64 + r) * 2048 + bj*64 + cl);
    tbuf[cl+0][r] = f2bf(v.x);
    tbuf[cl+1][r] = f2bf(v.y);
    tbuf[cl+2][r] = f2bf(v.z);
    tbuf[cl+3][r] = f2bf(v.w);
  }
  __syncthreads();
  int n = tid >> 2, ch = tid & 3;
  const ushort* p = &tbuf[n][ch*16];
  unsigned pk[8];
  #pragma unroll
  for (int j = 0; j < 8; ++j) pk[j] = (unsigned)p[2*j] | ((unsigned)p[2*j+1] << 16);
  ushort* d = dst + (size_t)(bj*64 + n) * 2048 + bi*64 + ch*16;
  uint4 o0, o1;
  o0.x = pk[0]; o0.y = pk[1]; o0.z = pk[2]; o0.w = pk[3];
  o1.x = pk[4]; o1.y = pk[5]; o1.z = pk[6]; o1.w = pk[7];
  *(uint4*)(d) = o0;
  *(uint4*)(d + 8) = o1;
}

// =========================================================================
// GEMM1: inter = silu(x@wi0) * (x@wi1).  Tile 256(M)x128(N), BK=64, 8 waves.
// 8-phase schedule, counted vmcnt(6). LDS: 2 dbuf x [A0,A1,B0(w0),B1(w1)] x 16KB.
// =========================================================================
__global__ __launch_bounds__(512, 2) void gemm1_kernel(
    const ushort* __restrict__ xb, const ushort* __restrict__ w0t,
    const ushort* __restrict__ w1t, const int* __restrict__ row_token,
    const int* __restrict__ poff, ushort* __restrict__ inter) {
  const int ct = blockIdx.x;             // 0..15 (128-col tiles of I)
  const int rt = blockIdx.y;             // 0..71
  const int row0 = rt * 256;
  if (row0 >= poff[NEXP]) return;
  int e = 0;
  #pragma unroll
  for (int i = 1; i < NEXP; ++i) e += (row0 >= poff[i]);

  __shared__ __align__(16) char sm[131072];
  const int tid = threadIdx.x;
  const int w = tid >> 6, l = tid & 63;
  const int wr = w >> 2, wc = w & 3;     // 2M x 4N waves; wave out 128x32 (x2 gemms)
  const int fr = l & 15, kq = l >> 4;

  // ---- staging precompute (linear LDS dest, inverse-swizzled global src) ----
  const int mloc = tid >> 3;                                  // row within half (li adds 64)
  const int kl = ((tid & 7) ^ (mloc & 7)) << 3;               // element offset in 64-elem K row
  const ushort* aP[2][2]; const ushort* b0P[2]; const ushort* b1P[2];
  #pragma unroll
  for (int h = 0; h < 2; ++h)
    #pragma unroll
    for (int li = 0; li < 2; ++li) {
      int tok = row_token[row0 + h*128 + li*64 + mloc];
      aP[h][li] = xb + (size_t)tok * DDIM + kl;
    }
  #pragma unroll
  for (int li = 0; li < 2; ++li) {
    int n = ct*128 + li*64 + mloc;
    b0P[li] = w0t + ((size_t)e * IDIM + n) * DDIM + kl;
    b1P[li] = w1t + ((size_t)e * IDIM + n) * DDIM + kl;
  }
  const int dOff = tid * 16;

#define S_A(h, dd, tt) do { int ka = (tt)*64; char* db = sm + (dd)*65536 + (h)*16384 + dOff; \
  glds16(aP[h][0] + ka, db); glds16(aP[h][1] + ka, db + 8192); } while(0)
#define S_B0(dd, tt) do { int ka = (tt)*64; char* db = sm + (dd)*65536 + 32768 + dOff; \
  glds16(b0P[0] + ka, db); glds16(b0P[1] + ka, db + 8192); } while(0)
#define S_B1(dd, tt) do { int ka = (tt)*64; char* db = sm + (dd)*65536 + 49152 + dOff; \
  glds16(b1P[0] + ka, db); glds16(b1P[1] + ka, db + 8192); } while(0)

  // ---- ds_read offsets (swizzled chunk; row&7 == fr&7 for all frags) ----
  const int pc0 = ((kq ^ (fr & 7)) << 4);
  const int pc1 = (((4 + kq) ^ (fr & 7)) << 4);
  const int aBase = wr*16384 + fr*128;
  const int bBase = 32768 + (wc*32 + fr)*128;

#define RD_A(mq) do { const char* p_ = cur + aBase + (mq)*8192; \
  _Pragma("unroll") for (int mi = 0; mi < 4; ++mi) { \
    a[mi][0] = *(const short8*)(p_ + mi*2048 + pc0); \
    a[mi][1] = *(const short8*)(p_ + mi*2048 + pc1); } } while(0)
#define RD_B(dst_, gg) do { const char* p_ = cur + bBase + (gg)*16384; \
  _Pragma("unroll") for (int ni = 0; ni < 2; ++ni) { \
    dst_[ni][0] = *(const short8*)(p_ + ni*2048 + pc0); \
    dst_[ni][1] = *(const short8*)(p_ + ni*2048 + pc1); } } while(0)
#define MM(accv, mq, bb) do { __builtin_amdgcn_s_setprio(1); \
  _Pragma("unroll") for (int mi = 0; mi < 4; ++mi) \
  _Pragma("unroll") for (int ni = 0; ni < 2; ++ni) { \
    accv[(mq)*4+mi][ni] = __builtin_amdgcn_mfma_f32_16x16x32_bf16(a[mi][0], bb[ni][0], accv[(mq)*4+mi][ni], 0,0,0); \
    accv[(mq)*4+mi][ni] = __builtin_amdgcn_mfma_f32_16x16x32_bf16(a[mi][1], bb[ni][1], accv[(mq)*4+mi][ni], 0,0,0); } \
  __builtin_amdgcn_s_setprio(0); } while(0)

  f32x4 acc0[8][2], acc1[8][2];
  #pragma unroll
  for (int i = 0; i < 8; ++i)
    #pragma unroll
    for (int j = 0; j < 2; ++j) { acc0[i][j] = (f32x4)(0.f); acc1[i][j] = (f32x4)(0.f); }
  short8 a[4][2], b0v[2][2], b1v[2][2];

  // ---- prologue: tile0 all 4 halves -> d0; tile1 B0,B1,A0 -> d1 ----
  S_A(0,0,0); S_A(1,0,0); S_B0(0,0); S_B1(0,0);
  S_B0(1,1); S_B1(1,1); S_A(0,1,1);
  VMC6(); BAR();

  for (int t = 0; t < NTK; ++t) {
    const char* cur = sm + (t & 1) * 65536;
    const int d = t & 1;
    // p0: reads A(mq0)+B0; stage A1[d^1] <- t+1
    RD_A(0); RD_B(b0v, 0);
    if (t+1 < NTK) S_A(1, d^1, t+1);
    BAR(); MM(acc0, 0, b0v); BAR();
    // p1: reads B1; stage B0[d] <- t+2
    RD_B(b1v, 1);
    if (t+2 < NTK) S_B0(d, t+2);
    BAR(); MM(acc1, 0, b1v); BAR();
    // p2: reads A(mq1); stage B1[d] <- t+2
    RD_A(1);
    if (t+2 < NTK) S_B1(d, t+2);
    BAR(); MM(acc1, 1, b1v); BAR();
    // p3: stage A0[d] <- t+2; counted vmcnt guarantees t+1 resident
    if (t+2 < NTK) { S_A(0, d, t+2); VMC6(); } else { VMC0(); }
    BAR(); MM(acc0, 1, b0v); BAR();
  }
#undef S_A
#undef S_B0
#undef S_B1
#undef RD_A
#undef RD_B
#undef MM

  // ---- epilogue: SwiGLU -> bf16 inter ----
  #pragma unroll
  for (int ai = 0; ai < 8; ++ai)
    #pragma unroll
    for (int ni = 0; ni < 2; ++ni) {
      int col = ct*128 + wc*32 + ni*16 + fr;
      #pragma unroll
      for (int j = 0; j < 4; ++j) {
        int row = row0 + wr*128 + ai*16 + kq*4 + j;
        float h0 = acc0[ai][ni][j], h1 = acc1[ai][ni][j];
        float s = h0 / (1.f + __expf(-h0));
        inter[(size_t)row * IDIM + col] = f2bf(s * h1);
      }
    }
}

// =========================================================================
// GEMM2: out += w * (inter @ wo). Tile 256x256, BK=64, 8 waves, vmcnt(4).
// LDS: 2 dbuf x [A0,A1,B0,B1] x 16KB = 128KB (+tok/wgt).
// =========================================================================
__global__ __launch_bounds__(512, 2) void gemm2_kernel(
    const ushort* __restrict__ inter, const ushort* __restrict__ wot,
    const int* __restrict__ row_token, const float* __restrict__ row_weight,
    const int* __restrict__ poff, float* __restrict__ dout) {
  const int ct = blockIdx.x;             // 0..7 (256-col tiles of D)
  const int rt = blockIdx.y;
  const int row0 = rt * 256;
  if (row0 >= poff[NEXP]) return;
  int e = 0;
  #pragma unroll
  for (int i = 1; i < NEXP; ++i) e += (row0 >= poff[i]);

  __shared__ __align__(16) char sm[131072];
  __shared__ int tok_s[256];
  __shared__ float wgt_s[256];
  const int tid = threadIdx.x;
  if (tid < 256) { tok_s[tid] = row_token[row0 + tid]; wgt_s[tid] = row_weight[row0 + tid]; }

  const int w = tid >> 6, l = tid & 63;
  const int wr = w >> 2, wc = w & 3;     // wave out 128x64
  const int fr = l & 15, kq = l >> 4;

  const int mloc = tid >> 3;
  const int kl = ((tid & 7) ^ (mloc & 7)) << 3;
  const ushort* aP[2][2]; const ushort* bP[2][2];
  #pragma unroll
  for (int h = 0; h < 2; ++h)
    #pragma unroll
    for (int li = 0; li < 2; ++li) {
      aP[h][li] = inter + (size_t)(row0 + h*128 + li*64 + mloc) * IDIM + kl;
      int n = ct*256 + h*128 + li*64 + mloc;
      bP[h][li] = wot + ((size_t)e * DDIM + n) * IDIM + kl;
    }
  const int dOff = tid * 16;

#define S_A2(h, dd, tt) do { int ka = (tt)*64; char* db = sm + (dd)*65536 + (h)*16384 + dOff; \
  glds16(aP[h][0] + ka, db); glds16(aP[h][1] + ka, db + 8192); } while(0)
#define S_B2(h, dd, tt) do { int ka = (tt)*64; char* db = sm + (dd)*65536 + 32768 + (h)*16384 + dOff; \
  glds16(bP[h][0] + ka, db); glds16(bP[h][1] + ka, db + 8192); } while(0)

  const int pc0 = ((kq ^ (fr & 7)) << 4);
  const int pc1 = (((4 + kq) ^ (fr & 7)) << 4);
  const int aBase = wr*16384 + fr*128;
  const int bBase = 32768 + (wc>>1)*16384 + ((wc&1)*64 + fr)*128;

#define RD_A2(mq) do { const char* p_ = cur + aBase + (mq)*8192; \
  _Pragma("unroll") for (int mi = 0; mi < 4; ++mi) { \
    a[mi][0] = *(const short8*)(p_ + mi*2048 + pc0); \
    a[mi][1] = *(const short8*)(p_ + mi*2048 + pc1); } } while(0)
#define RD_B2(dst_, nq) do { const char* p_ = cur + bBase + (nq)*4096; \
  _Pragma("unroll") for (int ni = 0; ni < 2; ++ni) { \
    dst_[ni][0] = *(const short8*)(p_ + ni*2048 + pc0); \
    dst_[ni][1] = *(const short8*)(p_ + ni*2048 + pc1); } } while(0)
#define MM2(mq, nq, bb) do { __builtin_amdgcn_s_setprio(1); \
  _Pragma("unroll") for (int mi = 0; mi < 4; ++mi) \
  _Pragma("unroll") for (int ni = 0; ni < 2; ++ni) { \
    acc[(mq)*4+mi][(nq)*2+ni] = __builtin_amdgcn_mfma_f32_16x16x32_bf16(a[mi][0], bb[ni][0], acc[(mq)*4+mi][(nq)*2+ni], 0,0,0); \
    acc[(mq)*4+mi][(nq)*2+ni] = __builtin_amdgcn_mfma_f32_16x16x32_bf16(a[mi][1], bb[ni][1], acc[(mq)*4+mi][(nq)*2+ni], 0,0,0); } \
  __builtin_amdgcn_s_setprio(0); } while(0)

  f32x4 acc[8][4];
  #pragma unroll
  for (int i = 0; i < 8; ++i)
    #pragma unroll
    for (int j = 0; j < 4; ++j) acc[i][j] = (f32x4)(0.f);
  short8 a[4][2], bv0[2][2], bv1[2][2];

  // ---- prologue: tile0 4 halves -> d0; tile1 B0,B1 -> d1 ----
  S_A2(0,0,0); S_A2(1,0,0); S_B2(0,0,0); S_B2(1,0,0);
  S_B2(0,1,1); S_B2(1,1,1);
  VMC4(); BAR();

  for (int t = 0; t < NTK; ++t) {
    const char* cur = sm + (t & 1) * 65536;
    const int d = t & 1;
    // p0: reads A(mq0)+B(nq0); stage A0[d^1] <- t+1
    RD_A2(0); RD_B2(bv0, 0);
    if (t+1 < NTK) S_A2(0, d^1, t+1);
    BAR(); MM2(0, 0, bv0); BAR();
    // p1: reads B(nq1); stage A1[d^1] <- t+1
    RD_B2(bv1, 1);
    if (t+1 < NTK) S_A2(1, d^1, t+1);
    BAR(); MM2(0, 1, bv1); BAR();
    // p2: reads A(mq1); stage B0[d] <- t+2
    RD_A2(1);
    if (t+2 < NTK) S_B2(0, d, t+2);
    BAR(); MM2(1, 1, bv1); BAR();
    // p3: stage B1[d] <- t+2; counted vmcnt
    if (t+2 < NTK) { S_B2(1, d, t+2); VMC4(); } else { VMC0(); }
    BAR(); MM2(1, 0, bv0); BAR();
  }
#undef S_A2
#undef S_B2
#undef RD_A2
#undef RD_B2
#undef MM2

  // ---- epilogue: weighted atomic combine ----
  #pragma unroll
  for (int ai = 0; ai < 8; ++ai)
    #pragma unroll
    for (int aj = 0; aj < 4; ++aj) {
      int col = ct*256 + wc*64 + aj*16 + fr;
      #pragma unroll
      for (int j = 0; j < 4; ++j) {
        int rl2 = wr*128 + ai*16 + kq*4 + j;
        float wv = wgt_s[rl2];
        if (wv != 0.f) {
          int tk = tok_s[rl2];
          atomicAdd(&dout[(size_t)tk * DDIM + col], wv * acc[ai][aj][j]);
        }
      }
    }
}

extern "C" void kernel_launch(void* const* d_in, const int* in_sizes, int n_in,
                              void* d_out, int out_size, void* d_ws, size_t ws_size,
                              hipStream_t stream) {
  const float* x   = (const float*)d_in[0];
  const float* rl  = (const float*)d_in[1];
  const float* wi0 = (const float*)d_in[2];
  const float* wi1 = (const float*)d_in[3];
  const float* wo  = (const float*)d_in[4];
  float* out = (float*)d_out;

  char* ws = (char*)d_ws;
  ushort* xb    = (ushort*)(ws);                  // 33,554,432
  ushort* w0t   = (ushort*)(ws + 33554432ull);    // 67,108,864 (reused as wot after gemm1)
  ushort* w1t   = (ushort*)(ws + 100663296ull);   // 67,108,864
  ushort* inter = (ushort*)(ws + 167772160ull);   // 75,497,472 (18432 x 2048 bf16)
  char* ctrl    = ws + 243269632ull;
  int*   row_token  = (int*)(ctrl);               // 73,728
  float* row_weight = (float*)(ctrl + 73728);     // 73,728
  int*   cnt   = (int*)(ctrl + 147456);           // 32
  int*   fill  = (int*)(ctrl + 147488);           // 32
  int*   poff  = (int*)(ctrl + 147520);           // 36 (+pad)
  int*   pair_e = (int*)(ctrl + 147584);          // 65,536
  float* pair_w = (float*)(ctrl + 213120);        // 65,536

  hipMemsetAsync(ctrl, 0, 147520, stream);        // row_token/row_weight/cnt/fill
  router_kernel<<<T_TOK/256, 256, 0, stream>>>(rl, pair_e, pair_w, cnt);
  scan_kernel<<<1, 64, 0, stream>>>(cnt, poff);
  scatter_kernel<<<T_TOK/256, 256, 0, stream>>>(pair_e, pair_w, poff, fill, row_token, row_weight);
  convert_x_kernel<<<(T_TOK*DDIM)/(256*8), 256, 0, stream>>>(x, xb);
  transpose_w_kernel<<<dim3(32, 32, 16), 256, 0, stream>>>(wi0, w0t, wi1, w1t);
  hipMemsetAsync(d_out, 0, (size_t)out_size * sizeof(float), stream);
  gemm1_kernel<<<dim3(16, RTILES), 512, 0, stream>>>(xb, w0t, w1t, row_token, poff, inter);
  // wo transpose deferred: reuses w0t's buffer (gemm1 no longer needs it)
  transpose_w_kernel<<<dim3(32, 32, 8), 256, 0, stream>>>(wo, w0t, wo, w0t);
  gemm2_kernel<<<dim3(8, RTILES), 512, 0, stream>>>(inter, w0t, row_token, row_weight, poff, out);
}